// Round 1
// 60.096 us; speedup vs baseline: 1.0099x; 1.0099x over previous
//
#include <hip/hip_runtime.h>

// out[b] = sum_{m<64} prod_{l<256} eps[samples[b,l], m, l]
// B=4096, L=256, LOCAL_DIM=2, M=64.
//
// Log-space MFMA formulation (1-bit samples):
//   prod_l eps[s,m,l] = exp2( base[m] + sum_l s_bl * w[m,l] ),
//   w = log2(e1/e0)  (bf16, |w|<~0.6 -> quantization error ~1e-3/term,
//   random-sign accumulation -> output error ~0.1 abs vs threshold 2.18),
//   base[m] = sum_l log2 e0[m,l]  (fp32).
//
// v2: two-kernel split. The old kernel had every one of 256 blocks
// recompute the full 64x256 log2-transform (128 quarter-rate
// transcendentals + ~500 packing VALU per thread at 1 wave/SIMD) --
// 256x redundant, ~20 us. Now a one-shot prep kernel (4 blocks) computes
// W once into d_ws, ALREADY IN MFMA B-FRAGMENT ORDER, so the main kernel
// is pure {coalesced loads -> 8 MFMA -> exp2 -> reduce}: no LDS staging,
// no mid-kernel barrier, no transcendentals except 4 exp2 per lane.

#define LQ 256
#define MQ 64

typedef __attribute__((ext_vector_type(8))) short bf16x8;
typedef __attribute__((ext_vector_type(4))) float f32x4;
typedef __attribute__((ext_vector_type(4))) unsigned u32x4;

#if defined(__has_builtin) && __has_builtin(__builtin_amdgcn_logf)
#define LOG2F(x) __builtin_amdgcn_logf(x)
#else
#define LOG2F(x) __log2f(x)
#endif
#if defined(__has_builtin) && __has_builtin(__builtin_amdgcn_exp2f)
#define EXP2F(x) __builtin_amdgcn_exp2f(x)
#else
#define EXP2F(x) exp2f(x)
#endif

__device__ __forceinline__ unsigned short f2bf(float x) {
    unsigned u = __float_as_uint(x);
    u += 0x7FFFu + ((u >> 16) & 1u);   // RTNE
    return (unsigned short)(u >> 16);
}

// ---- Prep: 4 blocks (m-strips) x 512 threads (wave = k-step 0..7).
// Writes Wg in B-frag order: 16B vector index (strip*8 + k)*64 + lane
// holds W[m = strip*16 + (lane&15)][l = k*32 + (lane>>4)*8 + j], j=0..7.
// Also baseg[m] = sum_l log2 e0[m][l] (fp32). Fully overwrites every
// workspace byte the main kernel reads (workspace is poisoned per-iter).
__global__ __launch_bounds__(512) void qgps_prep(const float* __restrict__ eps,
                                                 unsigned short* __restrict__ Wg,
                                                 float* __restrict__ baseg) {
    __shared__ float bred[16][32];
    const int tid = threadIdx.x;
    const int k = tid >> 6;          // k-step (wave id)
    const int lane = tid & 63;
    const int strip = blockIdx.x;    // m-strip 0..3
    const int fr = lane & 15;
    const int q = lane >> 4;
    const int m = strip * 16 + fr;
    const int lb = k * 32 + q * 8;

    const float* e0 = eps + m * LQ + lb;
    const float* e1 = eps + MQ * LQ + m * LQ + lb;
    float4 a0 = *(const float4*)e0;
    float4 a1 = *(const float4*)(e0 + 4);
    float4 c0 = *(const float4*)e1;
    float4 c1 = *(const float4*)(e1 + 4);

    float l0 = LOG2F(a0.x), l1 = LOG2F(a0.y), l2 = LOG2F(a0.z), l3 = LOG2F(a0.w);
    float l4 = LOG2F(a1.x), l5 = LOG2F(a1.y), l6 = LOG2F(a1.z), l7 = LOG2F(a1.w);

    bf16x8 wv;
    wv[0] = (short)f2bf(LOG2F(c0.x) - l0);
    wv[1] = (short)f2bf(LOG2F(c0.y) - l1);
    wv[2] = (short)f2bf(LOG2F(c0.z) - l2);
    wv[3] = (short)f2bf(LOG2F(c0.w) - l3);
    wv[4] = (short)f2bf(LOG2F(c1.x) - l4);
    wv[5] = (short)f2bf(LOG2F(c1.y) - l5);
    wv[6] = (short)f2bf(LOG2F(c1.z) - l6);
    wv[7] = (short)f2bf(LOG2F(c1.w) - l7);
    ((bf16x8*)Wg)[(strip * 8 + k) * 64 + lane] = wv;   // coalesced 1KB/wave

    bred[fr][k * 4 + q] = ((l0 + l1) + (l2 + l3)) + ((l4 + l5) + (l6 + l7));
    __syncthreads();
    if (tid < 16) {
        float t = 0.f;
#pragma unroll
        for (int i = 0; i < 32; ++i) t += bred[tid][i];
        baseg[strip * 16 + tid] = t;
    }
}

// ---- Main: 256 blocks x 256 threads. Block bg: b-rows [bg*16, +16),
// wave w: m-strip [w*16, +16). No LDS staging, no mid-kernel barrier.
__global__ __launch_bounds__(256) void qgps_main(const int* __restrict__ samples,
                                                 const unsigned short* __restrict__ Wg,
                                                 const float* __restrict__ baseg,
                                                 float* __restrict__ out) {
    __shared__ float red[4][16];     // cross-wave out partials
    const int tid = threadIdx.x;
    const int w = tid >> 6;
    const int lane = tid & 63;
    const int b0 = blockIdx.x * 16;
    const int fr = lane & 15;
    const int ko = (lane >> 4) * 8;

    // B-frags: 8 coalesced 16B loads/lane, L2-resident (just written by prep).
    const bf16x8* Wv = (const bf16x8*)Wg + w * 8 * 64 + lane;
    bf16x8 bfr[8];
#pragma unroll
    for (int k = 0; k < 8; ++k) bfr[k] = Wv[k * 64];

    // A-frags straight from global: lane holds S[b0+(lane&15)][k*32+ko .. +8].
    // Wave reads 16 rows x 128B contiguous per k (2KB/instr-pair); the 4
    // waves of a block read the same 16KB tile -> merged in L2.
    const int4* sp = (const int4*)(samples + (b0 + fr) * LQ + ko);
    f32x4 acc = {0.f, 0.f, 0.f, 0.f};
#pragma unroll
    for (int k = 0; k < 8; ++k) {
        int4 v0 = sp[k * 8];
        int4 v1 = sp[k * 8 + 1];
        // s in {0,1}: packed bf16 pair = (s_lo | s_hi<<16) * 0x3F80
        // (2 VALU per pair vs 4-5 for cmp+cndmask packing).
        u32x4 u;
        u[0] = (unsigned)((v0.x | (v0.y << 16)) * 0x3F80);
        u[1] = (unsigned)((v0.z | (v0.w << 16)) * 0x3F80);
        u[2] = (unsigned)((v1.x | (v1.y << 16)) * 0x3F80);
        u[3] = (unsigned)((v1.z | (v1.w << 16)) * 0x3F80);
        acc = __builtin_amdgcn_mfma_f32_16x16x32_bf16(
            __builtin_bit_cast(bf16x8, u), bfr[k], acc, 0, 0, 0);
    }

    // Epilogue. C/D layout: col (lane&15) = m_local, row ((lane>>4)*4+reg)
    // = b_local. t = exp2(base[m] + acc).
    const float base = baseg[w * 16 + fr];
    float t0 = EXP2F(base + acc[0]);
    float t1 = EXP2F(base + acc[1]);
    float t2 = EXP2F(base + acc[2]);
    float t3 = EXP2F(base + acc[3]);
    // Sum over the 16 m-cols (lanes within each 16-lane group).
#pragma unroll
    for (int off = 1; off < 16; off <<= 1) {
        t0 += __shfl_xor(t0, off, 64);
        t1 += __shfl_xor(t1, off, 64);
        t2 += __shfl_xor(t2, off, 64);
        t3 += __shfl_xor(t3, off, 64);
    }
    if (fr == 0) {
        const int q = lane >> 4;
        red[w][q * 4 + 0] = t0;
        red[w][q * 4 + 1] = t1;
        red[w][q * 4 + 2] = t2;
        red[w][q * 4 + 3] = t3;
    }
    __syncthreads();
    if (tid < 16) {
        float o = (red[0][tid] + red[1][tid]) + (red[2][tid] + red[3][tid]);
        out[b0 + tid] = o;   // single write per b: no atomics, no zero-init
    }
}

extern "C" void kernel_launch(void* const* d_in, const int* in_sizes, int n_in,
                              void* d_out, int out_size, void* d_ws, size_t ws_size,
                              hipStream_t stream) {
    const int* samples = (const int*)d_in[0];   // (B, L) int32
    const float* eps = (const float*)d_in[1];   // (2, M, L) fp32
    float* out = (float*)d_out;                 // (B,) fp32

    // Workspace layout: Wg bf16 frag-ordered [32768 B] | base fp32 [256 B].
    unsigned short* Wg = (unsigned short*)d_ws;
    float* baseg = (float*)((char*)d_ws + 32768);
    (void)ws_size; (void)in_sizes; (void)n_in; (void)out_size;

    qgps_prep<<<4, 512, 0, stream>>>(eps, Wg, baseg);
    qgps_main<<<256, 256, 0, stream>>>(samples, Wg, baseg, out);
}